// Round 5
// baseline (579.734 us; speedup 1.0000x reference)
//
#include <hip/hip_runtime.h>
#include <hip/hip_fp16.h>
#include <stdint.h>

// ---------------------------------------------------------------------------
// QuantizedExpert: out = relu(x @ dq(W1)^T + b1) @ dq(W2)^T + b2
// HARNESS DTYPES: int8 inputs arrive widened to int32; fp16 scales as fp32.
// INT8 MFMA path: weights int4 exact in int8; x per-token symmetric int8;
// h per-token shifted-u8 (+128*rowsum(W2) epilogue correction).
// GEMM v5 (safe rework of v4): A-operand DIRECT from global (blocked layout
// [r/32][k/16][32][16], 1KB/wave coalesced loads, plain C++ derefs so the
// COMPILER owns all vmcnt) -- A never touches LDS.  B reg-staged (T14):
// plain global loads -> regs -> swizzled ds_write into 2x32KB LDS dbuf.
// No global_load_lds, no manual vmcnt anywhere; only manual sync is one
// conservative lgkmcnt(0)+s_barrier per K-tile.  Rationale: r1-r3 showed
// this barrier-locked template is bounded by the per-CU serial sum
// (matrix 2330 + LDS ~3300 cy/tile); cutting LDS to ~1450 lifts the
// ceiling from ~40% to ~62% MfmaUtil.
// ---------------------------------------------------------------------------

typedef __attribute__((ext_vector_type(4)))  int i32x4;
typedef __attribute__((ext_vector_type(16))) int i32x16;
typedef __attribute__((ext_vector_type(8))) _Float16 f16x8;

__device__ __forceinline__ float block_max(float m, int tid) {
    __shared__ float red[4];
#pragma unroll
    for (int off = 32; off; off >>= 1)
        m = fmaxf(m, __shfl_down(m, off, 64));
    if ((tid & 63) == 0) red[tid >> 6] = m;
    __syncthreads();
    m = fmaxf(fmaxf(red[0], red[1]), fmaxf(red[2], red[3]));
    __syncthreads();
    return m;
}

// ---- x [rows][4096] f32 -> int8 per-row symmetric, BLOCKED layout
// out int4 index = ((row>>5)*(ncols/16) + kc)*32 + (row&31), kc = col/16.
__global__ __launch_bounds__(256) void quant_x(
    const float* __restrict__ in, int4* __restrict__ out,
    float* __restrict__ rscale, int ncols)
{
    const int tid = threadIdx.x;
    const int row = blockIdx.x;
    const float4* r4 = (const float4*)(in + (size_t)row * ncols);
    float4 v[4];
    float m = 0.f;
#pragma unroll
    for (int k = 0; k < 4; ++k) {
        v[k] = r4[tid * 4 + k];
        m = fmaxf(m, fmaxf(fmaxf(fabsf(v[k].x), fabsf(v[k].y)),
                           fmaxf(fabsf(v[k].z), fabsf(v[k].w))));
    }
    m = block_max(m, tid);
    m = fmaxf(m, 1e-20f);
    const float inv = 127.f / m;
    if (tid == 0) rscale[row] = m / 127.f;
    union { int8_t b[16]; int4 w; } u;
#pragma unroll
    for (int k = 0; k < 4; ++k) {
        u.b[4 * k + 0] = (int8_t)__float2int_rn(v[k].x * inv);
        u.b[4 * k + 1] = (int8_t)__float2int_rn(v[k].y * inv);
        u.b[4 * k + 2] = (int8_t)__float2int_rn(v[k].z * inv);
        u.b[4 * k + 3] = (int8_t)__float2int_rn(v[k].w * inv);
    }
    out[((size_t)(row >> 5) * (ncols >> 4) + tid) * 32 + (row & 31)] = u.w;
}

// ---- h [rows][8192] f16 (>=0) -> shifted u8, BLOCKED layout; sh=max/255
__global__ __launch_bounds__(256) void quant_h(
    const _Float16* __restrict__ in, int4* __restrict__ out,
    float* __restrict__ rscale, int ncols)
{
    const int tid = threadIdx.x;
    const int row = blockIdx.x;
    const f16x8* rp = (const f16x8*)(in + (size_t)row * ncols);
    f16x8 v[2][2];
    float m = 0.f;
#pragma unroll
    for (int c = 0; c < 2; ++c) {
        const int kc = tid + c * 256;
        v[c][0] = rp[2 * kc];
        v[c][1] = rp[2 * kc + 1];
#pragma unroll
        for (int e = 0; e < 8; ++e)
            m = fmaxf(m, fmaxf((float)v[c][0][e], (float)v[c][1][e]));
    }
    m = block_max(m, tid);
    m = fmaxf(m, 1e-20f);
    const float inv = 255.f / m;
    if (tid == 0) rscale[row] = m / 255.f;
#pragma unroll
    for (int c = 0; c < 2; ++c) {
        const int kc = tid + c * 256;
        union { int8_t b[16]; int4 w; } u;
#pragma unroll
        for (int h = 0; h < 2; ++h)
#pragma unroll
            for (int e = 0; e < 8; ++e) {
                int q = __float2int_rn((float)v[c][h][e] * inv);
                q = q < 0 ? 0 : (q > 255 ? 255 : q);
                u.b[8 * h + e] = (int8_t)(q - 128);
            }
        out[((size_t)(row >> 5) * (ncols >> 4) + kc) * 32 + (row & 31)] = u.w;
    }
}

// ---- packed int4 (one byte per int32 word) -> int8 row-major; + row sums
__global__ __launch_bounds__(256) void expand_int4_i8(
    const int4* __restrict__ packed, int2* __restrict__ out,
    int* __restrict__ wsum, int n_i4)
{
    const int tid = threadIdx.x;
    const int row = blockIdx.x;
    const int4* prow = packed + (size_t)row * n_i4;
    int2* orow = out + (size_t)row * n_i4;
    int sum = 0;
    for (int j = tid; j < n_i4; j += 256) {
        int4 p = prow[j];
        int vals[4] = {p.x, p.y, p.z, p.w};
        union { int8_t b[8]; int2 w; } u;
#pragma unroll
        for (int b = 0; b < 4; ++b) {
            int by = (int)(int8_t)(vals[b] & 0xFF);
            int hi = by >> 4;
            int lo = ((by & 15) ^ 8) - 8;
            u.b[2 * b] = (int8_t)hi;
            u.b[2 * b + 1] = (int8_t)lo;
            sum += hi + lo;
        }
        orow[j] = u.w;
    }
    __shared__ int sred[4];
#pragma unroll
    for (int off = 32; off; off >>= 1) sum += __shfl_down(sum, off, 64);
    if ((tid & 63) == 0) sred[tid >> 6] = sum;
    __syncthreads();
    if (tid == 0) wsum[row] = sred[0] + sred[1] + sred[2] + sred[3];
}

// ---------------------------------------------------------------------------
// C = epi( A[M][K]i8 @ B[N][K]i8^T );  A BLOCKED, B row-major.
// 256x256 tile, BK=128B, 8 waves (2x4), wave 128x64 via 4x2 mfma 32x32x32_i8.
// LDS: B only, 2 x [256 rows][128B] = 64KB dbuf, phys chunk = logical^(row&7).
//
// Per tile t, 4 phases (X/Y alternate, af group g = 4t+ks):
//   ph0: ds_read bf(0),bf(1); glb-load bsr=B(t+1); MFMA(afX=g);   issue afX<-g+2
//   ph1: ds_read bf(2);                            MFMA(afY=g+1); issue afY<-g+3
//   ph2: ds_read bf(3);                            MFMA(afX=g+2); issue afX<-g+4
//   ph3:                                           MFMA(afY=g+3); issue afY<-g+5
//        ds_write bsr -> buf[(t+1)&1]; lgkmcnt(0); s_barrier
// All VMEM waits are compiler-inserted (plain loads).  Hazard audit:
//  - buf[(t+1)&1] writes: its readers finished in tile t-1, fenced by the
//    end-of-(t-1) lgkm(0)+barrier.
//  - buf[t&1] reads at t: written at t-1 ph3 before that same fence.
//  - af issues at ph2/ph3 guarded (t+1<NT) -> no OOB reads (g+2,g+3 always
//    in-bounds since g+3 <= 4*NT-1).
// ---------------------------------------------------------------------------
template <bool RELU, bool SHIFT, typename OutT>
__global__ __launch_bounds__(512, 2) void gemm_i8_ad(
    const int8_t* __restrict__ Ablk,   // blocked [M/32][K/16][32][16]
    const int8_t* __restrict__ B,      // row-major [N][K]
    OutT* __restrict__ C,
    const float* __restrict__ sa, const float* __restrict__ s,
    const float* __restrict__ bias, const int* __restrict__ wsum,
    int M, int N, int K)
{
    __shared__ alignas(16) char sB[2][256 * 128];

    const int tid  = threadIdx.x;
    const int lane = tid & 63;
    const int wave = tid >> 6;
    const int wm = wave >> 2;          // row half (128 rows)
    const int wn = wave & 3;           // col quarter (64 cols)

    // Chunked XCD swizzle (m157 form, nwg%8==0): XCD k owns a contiguous
    // new-bid range = 2 consecutive by-rows -> A-panel (2MB) L2-resident.
    int bid = blockIdx.y * gridDim.x + blockIdx.x;
    const int cpx = (gridDim.x * gridDim.y) >> 3;
    bid = (bid & 7) * cpx + (bid >> 3);
    const int bm = (bid / gridDim.x) * 256;
    const int bn = (bid % gridDim.x) * 256;

    // ---- B reg-staging geometry: thread -> 4 x 16B (rows br+64h, chunk bc)
    const int br = tid >> 3;
    const int bc = tid & 7;
    const int8_t* Bg2 = B + (size_t)(bn + br) * K + bc * 16;
    const size_t rK64 = (size_t)64 * K;
    int bw[4];
#pragma unroll
    for (int h = 0; h < 4; ++h)
        bw[h] = (br + 64 * h) * 128 + ((bc ^ (br & 7)) << 4);

    // ---- fragment geometry (mfma i8 32x32x32: m/n = lane&31, k-half = lane>>5)
    const int l31 = lane & 31;
    const int kh  = lane >> 5;
    int coff[4];
#pragma unroll
    for (int ks = 0; ks < 4; ++ks)
        coff[ks] = (((ks * 2 + kh) ^ (l31 & 7)) << 4);
    int bbase[2];
#pragma unroll
    for (int j = 0; j < 2; ++j) bbase[j] = (wn * 64 + j * 32 + l31) * 128;

    // ---- A direct: base pointers per row-block; group g at offset g*1024
    const int KC = K >> 4;
    const char* apb[4];
#pragma unroll
    for (int i = 0; i < 4; ++i)
        apb[i] = (const char*)Ablk +
                 ((size_t)((bm >> 5) + wm * 4 + i) * KC + (size_t)kh) * 512 +
                 (size_t)(l31 * 16);
    size_t ga = 0;

    i32x4 afX[4], afY[4], bfX[2], bfY[2], bsr[4];
    i32x16 acc[4][2] = {};
    const int NT = K >> 7;

#define SB0() __builtin_amdgcn_sched_barrier(0)
#define AFISSUE(AF)                                                         \
    do { _Pragma("unroll")                                                  \
        for (int i_ = 0; i_ < 4; ++i_)                                      \
            AF[i_] = *(const i32x4*)(apb[i_] + ga);                         \
        ga += 1024; } while (0)
#define BFREAD(BF, KS)                                                      \
    do { BF[0] = *(const i32x4*)(pB + bbase[0] + coff[KS]);                 \
         BF[1] = *(const i32x4*)(pB + bbase[1] + coff[KS]); } while (0)
#define MFMA8(AF, BF)                                                       \
    do { __builtin_amdgcn_s_setprio(1);                                     \
        _Pragma("unroll")                                                   \
        for (int i_ = 0; i_ < 4; ++i_) {                                    \
            acc[i_][0] = __builtin_amdgcn_mfma_i32_32x32x32_i8(             \
                AF[i_], BF[0], acc[i_][0], 0, 0, 0);                        \
            acc[i_][1] = __builtin_amdgcn_mfma_i32_32x32x32_i8(             \
                AF[i_], BF[1], acc[i_][1], 0, 0, 0);                        \
        }                                                                   \
        __builtin_amdgcn_s_setprio(0); } while (0)

    // ---- prologue: af g0,g1 in flight; B(0) -> regs -> LDS; fence
    AFISSUE(afX);
    AFISSUE(afY);
    {
#pragma unroll
        for (int h = 0; h < 4; ++h)
            bsr[h] = *(const i32x4*)(Bg2 + (size_t)h * rK64);
#pragma unroll
        for (int h = 0; h < 4; ++h)
            *(i32x4*)(sB[0] + bw[h]) = bsr[h];
    }
    asm volatile("s_waitcnt lgkmcnt(0)" ::: "memory");
    SB0();
    __builtin_amdgcn_s_barrier();
    SB0();

    for (int t = 0; t < NT; ++t) {
        const char* pB = sB[t & 1];
        char* pW = sB[(t + 1) & 1];
        const bool pf = (t + 1 < NT);

        // ---- ph0
        BFREAD(bfX, 0);
        BFREAD(bfY, 1);
        if (pf) {
            const int8_t* bsrc = Bg2 + (size_t)(t + 1) * 128;
#pragma unroll
            for (int h = 0; h < 4; ++h)
                bsr[h] = *(const i32x4*)(bsrc + (size_t)h * rK64);
        }
        SB0();
        MFMA8(afX, bfX);
        AFISSUE(afX);                          // g+2 (always in-bounds)
        SB0();
        // ---- ph1
        BFREAD(bfX, 2);
        SB0();
        MFMA8(afY, bfY);
        AFISSUE(afY);                          // g+3 (always in-bounds)
        SB0();
        // ---- ph2
        BFREAD(bfY, 3);
        SB0();
        MFMA8(afX, bfX);
        if (pf) AFISSUE(afX);                  // g+4
        SB0();
        // ---- ph3
        MFMA8(afY, bfY);
        if (pf) {
            AFISSUE(afY);                      // g+5
#pragma unroll
            for (int h = 0; h < 4; ++h)
                *(i32x4*)(pW + bw[h]) = bsr[h];
            asm volatile("s_waitcnt lgkmcnt(0)" ::: "memory");
            SB0();
            __builtin_amdgcn_s_barrier();
        }
        SB0();
    }
#undef SB0
#undef AFISSUE
#undef BFREAD
#undef MFMA8

    // epilogue: 32x32 C/D layout col=lane&31, row=(reg&3)+8*(reg>>2)+4*(lane>>5)
#pragma unroll
    for (int j = 0; j < 2; ++j) {
        const int n  = bn + wn * 64 + j * 32 + l31;
        const float sc = s[n];
        const float bs = bias[n];
        const int shf = SHIFT ? 128 * wsum[n] : 0;
#pragma unroll
        for (int i = 0; i < 4; ++i) {
            const int mb = bm + wm * 128 + i * 32 + 4 * kh;
#pragma unroll
            for (int reg = 0; reg < 16; ++reg) {
                const int m = mb + (reg & 3) + 8 * (reg >> 2);
                float v = (float)(acc[i][j][reg] + shf) * sc * sa[m] + bs;
                if (RELU) v = v > 0.f ? v : 0.f;
                C[(size_t)m * N + n] = (OutT)v;
            }
        }
    }
}

extern "C" void kernel_launch(void* const* d_in, const int* in_sizes, int n_in,
                              void* d_out, int out_size, void* d_ws, size_t ws_size,
                              hipStream_t stream)
{
    const float* x   = (const float*)d_in[0];
    const int4*  w1p = (const int4*)d_in[1];     // int8 widened to int32
    const float* s1  = (const float*)d_in[2];    // fp16 widened to fp32
    const float* b1  = (const float*)d_in[3];
    const int4*  w2p = (const int4*)d_in[4];
    const float* s2  = (const float*)d_in[5];
    const float* b2  = (const float*)d_in[6];
    float* out = (float*)d_out;

    const int d    = in_sizes[6];        // 4096
    const int d2   = in_sizes[3];        // 8192
    const int Ntok = in_sizes[0] / d;    // 4096

    char* ws = (char*)d_ws;
    int8_t*   xq = (int8_t*)ws;                               // 16.8 MB (blocked)
    int8_t*   wq = (int8_t*)(ws + (size_t)Ntok * d);          // 33.6 MB (W1/W2 shared)
    _Float16* hb = (_Float16*)(ws + (size_t)Ntok * d + (size_t)d2 * d);        // 67 MB
    int8_t*   hq = (int8_t*)((char*)hb + (size_t)Ntok * d2 * 2);               // 33.6 MB (blocked)
    float*    sx = (float*)((char*)hq + (size_t)Ntok * d2);   // 16 KB
    float*    sh = sx + Ntok;                                 // 16 KB
    int*      wsum = (int*)(sh + Ntok);                       // 32 KB

    // 1. x -> int8 per-row, blocked layout
    quant_x<<<Ntok, 256, 0, stream>>>(x, (int4*)xq, sx, d);
    // 2. W1 int4 -> int8 row-major
    expand_int4_i8<<<d2, 256, 0, stream>>>(w1p, (int2*)wq, wsum, d / 8);
    // 3. h = relu(s1[n]*sx[m]*acc + b1[n]) -> f16
    {
        dim3 grid(d2 / 256, Ntok / 256);
        gemm_i8_ad<true, false, _Float16><<<grid, 512, 0, stream>>>(
            xq, wq, hb, sx, s1, b1, nullptr, Ntok, d2, d);
    }
    // 4. h -> shifted-u8 per-row, blocked layout
    quant_h<<<Ntok, 256, 0, stream>>>(hb, (int4*)hq, sh, d2);
    // 5. W2 int4 -> int8 + row sums
    expand_int4_i8<<<d, 256, 0, stream>>>(w2p, (int2*)wq, wsum, d2 / 8);
    // 6. out = s2[n]*sh[m]*(acc + 128*wsum[n]) + b2[n] -> f32
    {
        dim3 grid(d / 256, Ntok / 256);
        gemm_i8_ad<false, true, float><<<grid, 512, 0, stream>>>(
            hq, wq, out, sh, s2, b2, wsum, Ntok, d, d2);
    }
}

// Round 6
// 484.667 us; speedup vs baseline: 1.1961x; 1.1961x over previous
//
#include <hip/hip_runtime.h>
#include <hip/hip_fp16.h>
#include <stdint.h>

// ---------------------------------------------------------------------------
// QuantizedExpert: out = relu(x @ dq(W1)^T + b1) @ dq(W2)^T + b2
// HARNESS DTYPES: int8 inputs arrive widened to int32; fp16 scales as fp32.
// INT8 MFMA path: weights int4 are exact in int8; x quantized per-token
// (signed, absmax/127); h quantized per-token shifted-u8 (h>=0 after relu:
// store round(h*255/max)-128, corrected by +128*rowsum(W2) in epilogue).
// GEMM v6 = v3 (best verified: ks-phase counted-lgkm schedule, 256x256 tile,
// BK=128B, 8 waves 2x4, mfma_i32_32x32x32_i8, XOR-swizzled LDS, counted
// vmcnt(4), column-XCD mapping) + ZERO-VALU addressing:
//   - K-loop unrolled x2 (buffer parity static per copy)
//   - 16 lane-resident LDS base pointers; frag selects via ds_read offset:imm
//   - DMA source pointers advanced by +=128/tile (4 v_add vs ~40)
// Rationale: v3 PMC decomposition 5900 cy/tile = matrix 2330 + LDS ~1800 +
// VALU ~990 + waits ~800, summing under barrier-lock; VALU is the removable
// term (address recomputation per ds_read / per DMA).
// ---------------------------------------------------------------------------

typedef __attribute__((ext_vector_type(4)))  int i32x4;
typedef __attribute__((ext_vector_type(16))) int i32x16;
typedef __attribute__((ext_vector_type(8))) _Float16 f16x8;

__device__ __forceinline__ void load_lds16(const void* g, void* l) {
    __builtin_amdgcn_global_load_lds(
        (__attribute__((address_space(1))) void*)(void*)g,
        (__attribute__((address_space(3))) void*)(void*)l,
        16, 0, 0);
}

__device__ __forceinline__ float block_max(float m, int tid) {
    __shared__ float red[4];
#pragma unroll
    for (int off = 32; off; off >>= 1)
        m = fmaxf(m, __shfl_down(m, off, 64));
    if ((tid & 63) == 0) red[tid >> 6] = m;
    __syncthreads();
    m = fmaxf(fmaxf(red[0], red[1]), fmaxf(red[2], red[3]));
    __syncthreads();
    return m;
}

// ---- x [rows][4096] f32 -> int8 per-row symmetric; sx[row] = absmax/127
__global__ __launch_bounds__(256) void quant_x(
    const float* __restrict__ in, int* __restrict__ out,
    float* __restrict__ rscale, int ncols)
{
    const int tid = threadIdx.x;
    const int row = blockIdx.x;
    const float4* rp = (const float4*)(in + (size_t)row * ncols);
    const int nf4 = ncols / 4;                  // 1024
    float4 v[4];
    float m = 0.f;
#pragma unroll
    for (int k = 0; k < 4; ++k) {
        v[k] = rp[k * 256 + tid];
        m = fmaxf(m, fmaxf(fmaxf(fabsf(v[k].x), fabsf(v[k].y)),
                           fmaxf(fabsf(v[k].z), fabsf(v[k].w))));
    }
    m = block_max(m, tid);
    m = fmaxf(m, 1e-20f);
    const float inv = 127.f / m;
    if (tid == 0) rscale[row] = m / 127.f;
    int* orow = out + (size_t)row * nf4;
#pragma unroll
    for (int k = 0; k < 4; ++k) {
        int q0 = __float2int_rn(v[k].x * inv);
        int q1 = __float2int_rn(v[k].y * inv);
        int q2 = __float2int_rn(v[k].z * inv);
        int q3 = __float2int_rn(v[k].w * inv);
        orow[k * 256 + tid] = (q0 & 0xFF) | ((q1 & 0xFF) << 8) |
                              ((q2 & 0xFF) << 16) | ((q3 & 0xFF) << 24);
    }
}

// ---- h [rows][8192] f16 (>=0) -> shifted u8: round(h*255/max)-128; sh=max/255
__global__ __launch_bounds__(256) void quant_h(
    const _Float16* __restrict__ in, int2* __restrict__ out,
    float* __restrict__ rscale, int ncols)
{
    const int tid = threadIdx.x;
    const int row = blockIdx.x;
    const f16x8* rp = (const f16x8*)(in + (size_t)row * ncols);
    const int nv = ncols / 8;                   // 1024
    f16x8 v[4];
    float m = 0.f;
#pragma unroll
    for (int k = 0; k < 4; ++k) {
        v[k] = rp[k * 256 + tid];
#pragma unroll
        for (int e = 0; e < 8; ++e) m = fmaxf(m, (float)v[k][e]);
    }
    m = block_max(m, tid);
    m = fmaxf(m, 1e-20f);
    const float inv = 255.f / m;
    if (tid == 0) rscale[row] = m / 255.f;
    int2* orow = out + (size_t)row * nv;
#pragma unroll
    for (int k = 0; k < 4; ++k) {
        union { int8_t b[8]; int2 w; } u;
#pragma unroll
        for (int e = 0; e < 8; ++e) {
            int q = __float2int_rn((float)v[k][e] * inv);
            q = q < 0 ? 0 : (q > 255 ? 255 : q);
            u.b[e] = (int8_t)(q - 128);
        }
        orow[k * 256 + tid] = u.w;
    }
}

// ---- packed int4 (one byte per int32 word) -> int8; also row sums (for shift)
__global__ __launch_bounds__(256) void expand_int4_i8(
    const int4* __restrict__ packed, int2* __restrict__ out,
    int* __restrict__ wsum, int n_i4)
{
    const int tid = threadIdx.x;
    const int row = blockIdx.x;
    const int4* prow = packed + (size_t)row * n_i4;
    int2* orow = out + (size_t)row * n_i4;
    int sum = 0;
    for (int j = tid; j < n_i4; j += 256) {
        int4 p = prow[j];
        int vals[4] = {p.x, p.y, p.z, p.w};
        union { int8_t b[8]; int2 w; } u;
#pragma unroll
        for (int b = 0; b < 4; ++b) {
            int by = (int)(int8_t)(vals[b] & 0xFF);
            int hi = by >> 4;
            int lo = ((by & 15) ^ 8) - 8;
            u.b[2 * b] = (int8_t)hi;
            u.b[2 * b + 1] = (int8_t)lo;
            sum += hi + lo;
        }
        orow[j] = u.w;
    }
    __shared__ int sred[4];
#pragma unroll
    for (int off = 32; off; off >>= 1) sum += __shfl_down(sum, off, 64);
    if ((tid & 63) == 0) sred[tid >> 6] = sum;
    __syncthreads();
    if (tid == 0) wsum[row] = sred[0] + sred[1] + sred[2] + sred[3];
}

// ---------------------------------------------------------------------------
// C = epi( A[M][K]i8 @ B[N][K]i8^T );  epi = sa[m]*s[n]*(acc + shift) + bias[n]
// 256x256 tile, BK=128B, 8 waves (2x4), wave 128x64 via 4x2 mfma 32x32x32_i8.
// LDS: sAB[buf][A 0..32K | B 32K..64K] x2 = 128 KiB dbuf; 16B-chunk XOR
// swizzle phys = logical ^ (row&7).
//
// K-tile schedule (v3's counted-lgkm ks-phase pipeline, 2 barriers/tile):
//   vmcnt(4) [B(t+1) in flight]; s_barrier
//   init: read frags(0) [6 ds_read]; stage A(t+1) [4 DMA]
//   ph0:  read frags(1); lgkm(6) -> MFMA8(0)
//   ph1:  read frags(2); lgkm(6) -> MFMA8(1)
//   ph2:  read frags(3); lgkm(6) -> MFMA8(2)
//   ph3:  lgkm(0); s_barrier; stage B(t+2) [4 DMA]; MFMA8(3)
// Unrolled x2 so buffer parity is static: all ds_read = base-reg + offset:imm
// (zero per-read VALU); DMA src ptrs advance +=128/tile.
// vmcnt: per tile issues A(t+1)4 then B(t+2)4; at tile start outstanding <=
// [B(t),A(t),B(t+1)] -> vmcnt(4) completes A(t)+older, keeps B(t+1).
// ---------------------------------------------------------------------------
template <bool RELU, bool SHIFT, typename OutT>
__global__ __launch_bounds__(512, 2) void gemm_i8_256(
    const int8_t* __restrict__ A, const int8_t* __restrict__ B,
    OutT* __restrict__ C,
    const float* __restrict__ sa,      // per-m dequant scale
    const float* __restrict__ s,       // per-n scale
    const float* __restrict__ bias,    // per-n bias
    const int* __restrict__ wsum,      // per-n row-sum of B (SHIFT only)
    int M, int N, int K)
{
    __shared__ alignas(1024) char sAB[2][65536];

    const int tid  = threadIdx.x;
    const int lane = tid & 63;
    const int wave = tid >> 6;
    const int wm = wave >> 2;          // 0..1: row half (128 rows)
    const int wn = wave & 3;           // 0..3: col quarter (64 cols)

    // Column-major per-XCD mapping: XCD k owns gridDim.x/8 consecutive
    // B-column tiles (B-panel fits its private 4MB L2); A streams. (v3)
    int bid = blockIdx.y * gridDim.x + blockIdx.x;
    const int xcd = bid & 7;
    const int idx = bid >> 3;
    const int cpx = gridDim.x >> 3;
    const int bx = xcd * cpx + idx / gridDim.y;
    const int by = idx % gridDim.y;
    const int bm = by * 256;
    const int bn = bx * 256;

    // ---- staging: thread stages 16B chunks; LDS dest linear (tid*16 within
    // 8KB half-region); global src pre-swizzled: phys chunk (tid&7) holds
    // logical chunk (tid&7)^(row&7).
    const int srow = tid >> 3;                        // 0..63
    const int scol = ((tid & 7) ^ (srow & 7)) << 4;
    const int ldst = tid * 16;
    const size_t rK64  = (size_t)64 * K;
    const size_t rK128 = (size_t)128 * K;

    const int8_t* gA = A + (size_t)(bm + srow) * K + scol;   // advances +=128/tile
    const int8_t* gB = B + (size_t)(bn + srow) * K + scol;

    auto stage_a = [&](int buf, int h) {
        const int8_t* g = gA + (size_t)h * rK128;
        char* l = &sAB[buf][h * 16384 + ldst];
        load_lds16(g, l);
        load_lds16(g + rK64, l + 8192);
    };
    auto stage_b = [&](int buf, int h) {
        const int8_t* g = gB + (size_t)h * rK128;
        char* l = &sAB[buf][32768 + h * 16384 + ldst];
        load_lds16(g, l);
        load_lds16(g + rK64, l + 8192);
    };

    // ---- lane-resident read bases (zero per-read VALU; frag -> offset:imm)
    const int l31 = lane & 31;
    const int kh  = lane >> 5;
    const char* rdA[2][4];
    const char* rdB[2][4];
#pragma unroll
    for (int ks = 0; ks < 4; ++ks) {
        const int lp = l31 * 128 + ((((ks << 1) | kh) ^ (l31 & 7)) << 4);
        rdA[0][ks] = &sAB[0][wm * 16384 + lp];
        rdA[1][ks] = &sAB[1][wm * 16384 + lp];
        rdB[0][ks] = &sAB[0][32768 + wn * 8192 + lp];
        rdB[1][ks] = &sAB[1][32768 + wn * 8192 + lp];
    }

    i32x4 afX[4], afY[4], bfX[2], bfY[2];
    i32x16 acc[4][2] = {};
    const int NT = K >> 7;                 // 32 or 64 (always even)

#define SB0() __builtin_amdgcn_sched_barrier(0)
#define LG6  asm volatile("s_waitcnt lgkmcnt(6)" ::: "memory")
#define LG0  asm volatile("s_waitcnt lgkmcnt(0)" ::: "memory")
#define READF(AF, BF, BUF, KS)                                             \
    do {                                                                   \
        BF[0] = *(const i32x4*)(rdB[BUF][KS]);                             \
        BF[1] = *(const i32x4*)(rdB[BUF][KS] + 4096);                      \
        AF[0] = *(const i32x4*)(rdA[BUF][KS]);                             \
        AF[1] = *(const i32x4*)(rdA[BUF][KS] + 4096);                      \
        AF[2] = *(const i32x4*)(rdA[BUF][KS] + 8192);                      \
        AF[3] = *(const i32x4*)(rdA[BUF][KS] + 12288);                     \
    } while (0)
#define MFMA8(AF, BF)                                                      \
    do { __builtin_amdgcn_s_setprio(1);                                    \
        _Pragma("unroll")                                                  \
        for (int i_ = 0; i_ < 4; ++i_) {                                   \
            acc[i_][0] = __builtin_amdgcn_mfma_i32_32x32x32_i8(            \
                AF[i_], BF[0], acc[i_][0], 0, 0, 0);                       \
            acc[i_][1] = __builtin_amdgcn_mfma_i32_32x32x32_i8(            \
                AF[i_], BF[1], acc[i_][1], 0, 0, 0);                       \
        }                                                                  \
        __builtin_amdgcn_s_setprio(0); } while (0)

    // ---- prologue: A(0)->buf0, B(0)->buf0, B(1)->buf1
    stage_a(0, 0); stage_a(0, 1); gA += 128;
    stage_b(0, 0); stage_b(0, 1); gB += 128;
    stage_b(1, 0); stage_b(1, 1); gB += 128;

    for (int t = 0; t < NT; t += 2) {
        const bool pf = (t + 2 < NT);

        // ================= tile t (buf 0) =================
        asm volatile("s_waitcnt vmcnt(4)" ::: "memory");
        __builtin_amdgcn_s_barrier();
        SB0();
        READF(afX, bfX, 0, 0);
        stage_a(1, 0); stage_a(1, 1); gA += 128;          // A(t+1), always valid
        SB0();
        READF(afY, bfY, 0, 1); SB0(); LG6; SB0(); MFMA8(afX, bfX);
        READF(afX, bfX, 0, 2); SB0(); LG6; SB0(); MFMA8(afY, bfY);
        READF(afY, bfY, 0, 3); SB0(); LG6; SB0(); MFMA8(afX, bfX);
        LG0; SB0();
        __builtin_amdgcn_s_barrier();
        if (pf) { stage_b(0, 0); stage_b(0, 1); gB += 128; }   // B(t+2)
        SB0();
        MFMA8(afY, bfY);

        // ================= tile t+1 (buf 1) =================
        if (pf) asm volatile("s_waitcnt vmcnt(4)" ::: "memory");
        else    asm volatile("s_waitcnt vmcnt(0)" ::: "memory");
        __builtin_amdgcn_s_barrier();
        SB0();
        READF(afX, bfX, 1, 0);
        if (pf) { stage_a(0, 0); stage_a(0, 1); gA += 128; }   // A(t+2)
        SB0();
        READF(afY, bfY, 1, 1); SB0(); LG6; SB0(); MFMA8(afX, bfX);
        READF(afX, bfX, 1, 2); SB0(); LG6; SB0(); MFMA8(afY, bfY);
        READF(afY, bfY, 1, 3); SB0(); LG6; SB0(); MFMA8(afX, bfX);
        LG0; SB0();
        __builtin_amdgcn_s_barrier();
        if (pf) { stage_b(1, 0); stage_b(1, 1); gB += 128; }   // B(t+3)
        SB0();
        MFMA8(afY, bfY);
    }
#undef SB0
#undef LG6
#undef LG0
#undef READF
#undef MFMA8

    // epilogue: 32x32 C/D layout col=lane&31, row=(reg&3)+8*(reg>>2)+4*(lane>>5)
#pragma unroll
    for (int j = 0; j < 2; ++j) {
        const int n  = bn + wn * 64 + j * 32 + l31;
        const float sc = s[n];
        const float bs = bias[n];
        const int shf = SHIFT ? 128 * wsum[n] : 0;
#pragma unroll
        for (int i = 0; i < 4; ++i) {
            const int mb = bm + wm * 128 + i * 32 + 4 * kh;
#pragma unroll
            for (int reg = 0; reg < 16; ++reg) {
                const int m = mb + (reg & 3) + 8 * (reg >> 2);
                float v = (float)(acc[i][j][reg] + shf) * sc * sa[m] + bs;
                if (RELU) v = v > 0.f ? v : 0.f;
                C[(size_t)m * N + n] = (OutT)v;
            }
        }
    }
}

extern "C" void kernel_launch(void* const* d_in, const int* in_sizes, int n_in,
                              void* d_out, int out_size, void* d_ws, size_t ws_size,
                              hipStream_t stream)
{
    const float* x   = (const float*)d_in[0];
    const int4*  w1p = (const int4*)d_in[1];     // int8 widened to int32
    const float* s1  = (const float*)d_in[2];    // fp16 widened to fp32
    const float* b1  = (const float*)d_in[3];
    const int4*  w2p = (const int4*)d_in[4];
    const float* s2  = (const float*)d_in[5];
    const float* b2  = (const float*)d_in[6];
    float* out = (float*)d_out;

    const int d    = in_sizes[6];        // 4096
    const int d2   = in_sizes[3];        // 8192
    const int Ntok = in_sizes[0] / d;    // 4096

    char* ws = (char*)d_ws;
    int8_t*   xq = (int8_t*)ws;                               // 16.8 MB
    int8_t*   wq = (int8_t*)(ws + (size_t)Ntok * d);          // 33.6 MB (W1/W2 shared)
    _Float16* hb = (_Float16*)(ws + (size_t)Ntok * d + (size_t)d2 * d);        // 67 MB
    int8_t*   hq = (int8_t*)((char*)hb + (size_t)Ntok * d2 * 2);               // 33.6 MB
    float*    sx = (float*)((char*)hq + (size_t)Ntok * d2);   // 16 KB
    float*    sh = sx + Ntok;                                 // 16 KB
    int*      wsum = (int*)(sh + Ntok);                       // 32 KB

    // 1. x -> int8 per-row
    quant_x<<<Ntok, 256, 0, stream>>>(x, (int*)xq, sx, d);
    // 2. W1 int4 -> int8
    expand_int4_i8<<<d2, 256, 0, stream>>>(w1p, (int2*)wq, wsum, d / 8);
    // 3. h = relu(s1[n]*sx[m]*acc + b1[n]) -> f16
    {
        dim3 grid(d2 / 256, Ntok / 256);
        gemm_i8_256<true, false, _Float16><<<grid, 512, 0, stream>>>(
            xq, wq, hb, sx, s1, b1, nullptr, Ntok, d2, d);
    }
    // 4. h -> shifted-u8 per-row
    quant_h<<<Ntok, 256, 0, stream>>>(hb, (int2*)hq, sh, d2);
    // 5. W2 int4 -> int8 + row sums
    expand_int4_i8<<<d, 256, 0, stream>>>(w2p, (int2*)wq, wsum, d2 / 8);
    // 6. out = s2[n]*sh[m]*(acc + 128*wsum[n]) + b2[n] -> f32
    {
        dim3 grid(d / 256, Ntok / 256);
        gemm_i8_256<false, true, float><<<grid, 512, 0, stream>>>(
            hq, wq, out, sh, s2, b2, wsum, Ntok, d, d2);
    }
}